// Round 3
// baseline (2367.996 us; speedup 1.0000x reference)
//
#include <hip/hip_runtime.h>

#define TOK_D 128
#define NF 64
#define ROWLEN 4128   // 15*128 + 16*128 + 160
#define OUTLEN 192
#define REC 68        // LDS record stride (floats): [0]=m,[1]=s,[2..3]=pad,[4..68)=o[64]

struct P {
  const float* inputs;
  const float* wq[2]; const float* bq[2];
  const float* wk[2]; const float* bk[2];
  const float* wv[2]; const float* bv[2];
  const float* gq[2]; const float* bgq[2];
  const float* gk[2]; const float* bgk[2];
  const float* gv[2]; const float* bgv[2];
  const float* w1[2]; const float* b1[2];
  const float* w2[2]; const float* b2[2];
  const float* fcw;   const float* fcb;
  float* out;
};

// acc[f] = b[f] + sum_k w[f*K+k] * x[k]   (f = 0..63, weights wave-uniform -> s_load)
template<int K>
__device__ __forceinline__ void projK(float* acc, const float* w, const float* b, const float* x)
{
#pragma unroll
  for (int f = 0; f < NF; ++f) acc[f] = b[f];
#pragma unroll 1
  for (int kc = 0; kc < K; kc += 8) {
    const float4 xa = *reinterpret_cast<const float4*>(x + kc);
    const float4 xb = *reinterpret_cast<const float4*>(x + kc + 4);
    const float xv[8] = {xa.x, xa.y, xa.z, xa.w, xb.x, xb.y, xb.z, xb.w};
#pragma unroll
    for (int f = 0; f < NF; ++f) {
      const float* wr = w + f * K + kc;
#pragma unroll
      for (int j = 0; j < 8; ++j) acc[f] = fmaf(wr[j], xv[j], acc[f]);
    }
  }
}

__device__ __forceinline__ void ln64(float* v, const float* g, const float* b)
{
  float m = 0.f;
#pragma unroll
  for (int f = 0; f < NF; ++f) m += v[f];
  m *= (1.f / NF);
  float var = 0.f;
#pragma unroll
  for (int f = 0; f < NF; ++f) { const float d = v[f] - m; var = fmaf(d, d, var); }
  var *= (1.f / NF);
  const float rs = rsqrtf(var + 1e-6f);
#pragma unroll
  for (int f = 0; f < NF; ++f) v[f] = (v[f] - m) * rs * g[f] + b[f];
}

__global__ __launch_bounds__(256, 2) void fused_selfattn(P p)
{
  __shared__ float part[4][64][REC];   // 69,632 B

  const int wave = __builtin_amdgcn_readfirstlane((int)(threadIdx.x >> 6));
  const int lane = threadIdx.x & 63;
  const int row  = (blockIdx.x << 6) + lane;
  const int g    = wave >> 1;          // 0 = ally, 1 = enemy
  const int half = wave & 1;

  const float* xrow = p.inputs + (size_t)row * ROWLEN;
  const float* own  = xrow + (ROWLEN - TOK_D);       // last 128 cols
  const float* kvb  = xrow + g * (15 * TOK_D);       // ally @0, enemy @1920
  const int ntok = g ? 16 : 15;
  const int t0 = half ? 8 : 0;
  const int t1 = half ? ntok : 8;

  // ---- q = LN(own @ wq.T + bq) ----
  float q[NF];
  projK<TOK_D>(q, p.wq[g], p.bq[g], own);
  ln64(q, p.gq[g], p.bgq[g]);

  // ---- online softmax over this wave's token slice ----
  float o[NF];
#pragma unroll
  for (int f = 0; f < NF; ++f) o[f] = 0.f;
  float mrun = -1e30f, srun = 0.f;

  for (int t = t0; t < t1; ++t) {
    const float* x = kvb + t * TOK_D;
    float acc[NF];
    projK<TOK_D>(acc, p.wk[g], p.bk[g], x);
    ln64(acc, p.gk[g], p.bgk[g]);
    float sc = 0.f;
#pragma unroll
    for (int f = 0; f < NF; ++f) sc = fmaf(q[f], acc[f], sc);
    sc *= 0.125f;                                     // 1/sqrt(64)

    projK<TOK_D>(acc, p.wv[g], p.bv[g], x);           // v into same regs
    ln64(acc, p.gv[g], p.bgv[g]);

    const float mn = fmaxf(mrun, sc);
    const float c  = __expf(mrun - mn);
    const float e  = __expf(sc - mn);
    srun = srun * c + e;
#pragma unroll
    for (int f = 0; f < NF; ++f) o[f] = o[f] * c + e * acc[f];
    mrun = mn;
  }

  // ---- publish partial (m, s, o) ----
  {
    float* rec = &part[wave][lane][0];
    rec[0] = mrun;
    rec[1] = srun;
#pragma unroll
    for (int f = 0; f < NF; f += 4)
      *reinterpret_cast<float4*>(rec + 4 + f) = make_float4(o[f], o[f+1], o[f+2], o[f+3]);
  }

  // ---- wave 1: independent other-FC head (pre-barrier, for load balance) ----
  if (wave == 1) {
    const float* oth = xrow + 31 * TOK_D;             // col 3968, 160 floats
    float acc[NF];
    projK<160>(acc, p.fcw, p.fcb, oth);
    float* op = p.out + (size_t)row * OUTLEN + 128;
#pragma unroll
    for (int f = 0; f < NF; f += 4)
      *reinterpret_cast<float4*>(op + f) = make_float4(acc[f], acc[f+1], acc[f+2], acc[f+3]);
  }

  __syncthreads();

  // ---- waves 0/2: flash-merge the two partials, fc1+fc2, write out ----
  if (half == 0) {
    float* r0 = &part[wave][lane][0];
    float* r1 = &part[wave + 1][lane][0];
    const float m0 = r0[0], s0 = r0[1], m1 = r1[0], s1 = r1[1];
    const float M  = fmaxf(m0, m1);
    const float c0 = __expf(m0 - M), c1 = __expf(m1 - M);
    const float inv = 1.f / fmaf(s0, c0, s1 * c1);
#pragma unroll
    for (int f = 0; f < NF; ++f)
      r0[4 + f] = (r0[4 + f] * c0 + r1[4 + f] * c1) * inv;   // merged o -> LDS

    float h[NF];
    projK<64>(h, p.w1[g], p.b1[g], r0 + 4);           // fc1 reads o from LDS
#pragma unroll
    for (int f = 0; f < NF; ++f) r1[4 + f] = fmaxf(h[f], 0.f);  // relu(h) -> LDS

    float ao[NF];
    projK<64>(ao, p.w2[g], p.b2[g], r1 + 4);          // fc2 reads h from LDS

    float* op = p.out + (size_t)row * OUTLEN + g * 64;
#pragma unroll
    for (int f = 0; f < NF; f += 4)
      *reinterpret_cast<float4*>(op + f) = make_float4(ao[f], ao[f+1], ao[f+2], ao[f+3]);
  }
}

extern "C" void kernel_launch(void* const* d_in, const int* in_sizes, int n_in,
                              void* d_out, int out_size, void* d_ws, size_t ws_size,
                              hipStream_t stream) {
  (void)n_in; (void)d_ws; (void)ws_size; (void)out_size;
  const float* const* in = (const float* const*)d_in;
  P p;
  p.inputs = in[0];
  for (int g = 0; g < 2; ++g) {
    const int b = 1 + g * 16;
    p.wq[g]  = in[b + 0];  p.bq[g]  = in[b + 1];
    p.wk[g]  = in[b + 2];  p.bk[g]  = in[b + 3];
    p.wv[g]  = in[b + 4];  p.bv[g]  = in[b + 5];
    p.gq[g]  = in[b + 6];  p.bgq[g] = in[b + 7];
    p.gk[g]  = in[b + 8];  p.bgk[g] = in[b + 9];
    p.gv[g]  = in[b + 10]; p.bgv[g] = in[b + 11];
    p.w1[g]  = in[b + 12]; p.b1[g]  = in[b + 13];
    p.w2[g]  = in[b + 14]; p.b2[g]  = in[b + 15];
  }
  p.fcw = in[33];
  p.fcb = in[34];
  p.out = (float*)d_out;

  const int rows = in_sizes[0] / ROWLEN;      // 32768
  const int blocks = rows >> 6;               // 64 rows per block
  hipLaunchKernelGGL(fused_selfattn, dim3(blocks), dim3(256), 0, stream, p);
}

// Round 7
// 1004.795 us; speedup vs baseline: 2.3567x; 2.3567x over previous
//
#include <hip/hip_runtime.h>

typedef __attribute__((ext_vector_type(8))) short bf16x8;
typedef __attribute__((ext_vector_type(4))) float f32x4;
typedef __attribute__((ext_vector_type(4))) short short4v;
typedef unsigned short us;

#define ROWLEN 4128
#define OUTLEN 192

// ws layout (bf16 element offsets)
#define WKV_A 0
#define WKV_E 16384
#define WQC   32768
#define W1C   49152
#define W2C   57344
#define FCWC  65536

#define MFMA(a, b, c) __builtin_amdgcn_mfma_f32_16x16x32_bf16(a, b, c, 0, 0, 0)

// per-wave LDS slice (bytes): stg 5120 | oA 4096 | qF 2176 | oF 2176
#define L_OA 5120
#define L_QF 9216
#define L_OF 11392
#define L_WAVE 13568

__device__ __forceinline__ us f2bf(float f) {
  unsigned u = __float_as_uint(f);
  u += 0x7FFF + ((u >> 16) & 1);
  return (us)(u >> 16);
}
__device__ __forceinline__ short4v cvt4(float4 v) {
  short4v r;
  r.x = (short)f2bf(v.x); r.y = (short)f2bf(v.y);
  r.z = (short)f2bf(v.z); r.w = (short)f2bf(v.w);
  return r;
}
__device__ __forceinline__ bf16x8 ldb(const us* w, int n0, int K, int ks, int lane) {
  int idx = (n0 + (lane & 15)) * K + ks * 32 + (lane >> 4) * 8;
  return *(const bf16x8*)(w + idx);
}
__device__ __forceinline__ bf16x8 lda(const char* basep, int strideB, int ks, int lane) {
  int m = lane & 15;
  int byte = m * strideB + (ks * 32 + (lane >> 4) * 8) * 2;
  byte ^= (m & 7) << 4;
  return *(const bf16x8*)(basep + byte);
}

struct P {
  const float* inputs;
  const float* bq[2]; const float* gq[2]; const float* bgq[2];
  const float* bk[2]; const float* gk[2]; const float* bgk[2];
  const float* bv[2]; const float* gv[2]; const float* bgv[2];
  const float* b1[2]; const float* b2[2];
  const float* fcb;
  float* out;
};

__global__ void prep(const float* wq_a, const float* wk_a, const float* wv_a,
                     const float* w1_a, const float* w2_a,
                     const float* wq_e, const float* wk_e, const float* wv_e,
                     const float* w1_e, const float* w2_e,
                     const float* fcw, us* ws) {
  int t = blockIdx.x * 256 + threadIdx.x;
  int stride = gridDim.x * 256;
  for (int i = t; i < 16384; i += stride) {
    int n = i >> 7, k = i & 127;
    ws[WKV_A + i] = f2bf(n < 64 ? wk_a[n * 128 + k] : wv_a[(n - 64) * 128 + k]);
    ws[WKV_E + i] = f2bf(n < 64 ? wk_e[n * 128 + k] : wv_e[(n - 64) * 128 + k]);
    ws[WQC + i]   = f2bf(n < 64 ? wq_a[n * 128 + k] : wq_e[(n - 64) * 128 + k]);
  }
  for (int i = t; i < 8192; i += stride) {
    int n = i >> 7, k = i & 127;
    ws[W1C + i] = f2bf(k < 64 ? w1_a[n * 64 + k] : w1_e[n * 64 + k - 64]);
    ws[W2C + i] = f2bf(k < 64 ? w2_a[n * 64 + k] : w2_e[n * 64 + k - 64]);
  }
  for (int i = t; i < 10240; i += stride)
    ws[FCWC + i] = f2bf(fcw[i]);
}

__global__ __launch_bounds__(256, 2) void fused(P p, const us* ws) {
  __shared__ char lds_all[4][L_WAVE];          // 54,272 B
  const int wid  = threadIdx.x >> 6;
  const int lane = threadIdx.x & 63;
  const int l15  = lane & 15, lg = lane >> 4;
  char*  stg = &lds_all[wid][0];
  char*  oA  = &lds_all[wid][L_OA];
  float* qFp = (float*)&lds_all[wid][L_QF];    // [8][68]
  float* oFp = (float*)&lds_all[wid][L_OF];    // [8][68]
  const int rbase = (blockIdx.x << 4) + (wid << 2);
  const float* xb = p.inputs + (size_t)rbase * ROWLEN;

  // ---- phase 0: zero stg (5120) and oA (4096) ----
#pragma unroll
  for (int j = 0; j < 10; ++j)
    *(unsigned long long*)(stg + j * 512 + lane * 8) = 0ull;
#pragma unroll
  for (int j = 0; j < 8; ++j)
    *(unsigned long long*)(oA + j * 512 + lane * 8) = 0ull;

  // stage own rows [4][128] -> stg (rows 4-15 stay zero; in-order LDS per wave)
  {
    int i0 = lane * 4;
    float4 ov0 = *(const float4*)(xb + (i0 >> 7) * ROWLEN + 4000 + (i0 & 127));
    int b0 = i0 * 2; b0 ^= ((b0 >> 8) & 7) << 4;
    *(short4v*)(stg + b0) = cvt4(ov0);
    int i1 = 256 + lane * 4;
    float4 ov1 = *(const float4*)(xb + (i1 >> 7) * ROWLEN + 4000 + (i1 & 127));
    int b1 = i1 * 2; b1 ^= ((b1 >> 8) & 7) << 4;
    *(short4v*)(stg + b1) = cvt4(ov1);
  }
  __syncthreads();

  // ---- phase 1: q-GEMM + LN, publish q to qF (fp32) ----
  {
    f32x4 qa[8];
#pragma unroll
    for (int nt = 0; nt < 8; ++nt) { qa[nt].x = 0; qa[nt].y = 0; qa[nt].z = 0; qa[nt].w = 0; }
#pragma unroll
    for (int ks = 0; ks < 4; ++ks) {
      bf16x8 af = lda(stg, 256, ks, lane);
#pragma unroll
      for (int nt = 0; nt < 8; ++nt)
        qa[nt] = MFMA(af, ldb(ws + WQC, nt * 16, 128, ks, lane), qa[nt]);
    }
#pragma unroll
    for (int nt = 0; nt < 8; ++nt) {
      float b = p.bq[nt >> 2][(nt & 3) * 16 + l15];
#pragma unroll
      for (int reg = 0; reg < 4; ++reg) qa[nt][reg] += b;
    }
#pragma unroll
    for (int g = 0; g < 2; ++g) {
      float gv_[4], bv_[4];
#pragma unroll
      for (int nt = 0; nt < 4; ++nt) {
        gv_[nt] = p.gq[g][nt * 16 + l15];
        bv_[nt] = p.bgq[g][nt * 16 + l15];
      }
#pragma unroll
      for (int reg = 0; reg < 4; ++reg) {
        float s = qa[g*4+0][reg] + qa[g*4+1][reg] + qa[g*4+2][reg] + qa[g*4+3][reg];
        s += __shfl_xor(s, 1); s += __shfl_xor(s, 2); s += __shfl_xor(s, 4); s += __shfl_xor(s, 8);
        float mu = s * (1.f / 64.f);
        float v2 = 0.f;
#pragma unroll
        for (int nt = 0; nt < 4; ++nt) { float d = qa[g*4+nt][reg] - mu; v2 = fmaf(d, d, v2); }
        v2 += __shfl_xor(v2, 1); v2 += __shfl_xor(v2, 2); v2 += __shfl_xor(v2, 4); v2 += __shfl_xor(v2, 8);
        float rs = rsqrtf(v2 * (1.f / 64.f) + 1e-6f);
#pragma unroll
        for (int nt = 0; nt < 4; ++nt)
          qa[g*4+nt][reg] = (qa[g*4+nt][reg] - mu) * rs * gv_[nt] + bv_[nt];
      }
    }
    if (lg == 0) {
#pragma unroll
      for (int nt = 0; nt < 8; ++nt)
#pragma unroll
        for (int reg = 0; reg < 4; ++reg)
          qFp[((nt >> 2) * 4 + reg) * 68 + (nt & 3) * 16 + l15] = qa[nt][reg];
    }
  }
  __syncthreads();

  // ---- phase 2: per (group, row) attention ----
#pragma unroll
  for (int t = 0; t < 8; ++t) {
    const int g = t >> 2, r = t & 3;
    // stage kv tile [16][128] (fully overwrites bytes 0-4095)
#pragma unroll
    for (int j = 0; j < 8; ++j) {
      float4 w = *(const float4*)(xb + r * ROWLEN + g * 1920 + j * 256 + lane * 4);
      int i = j * 256 + lane * 4;
      int b = i * 2; b ^= ((b >> 8) & 7) << 4;
      *(short4v*)(stg + b) = cvt4(w);
    }
    __syncthreads();

    const us* wkv = ws + (g ? WKV_E : WKV_A);
    float bk_[4], gk_[4], bbk_[4], bvv_[4], gvv_[4], bbv_[4];
#pragma unroll
    for (int nt = 0; nt < 4; ++nt) {
      int f = nt * 16 + l15;
      bk_[nt] = p.bk[g][f]; gk_[nt] = p.gk[g][f]; bbk_[nt] = p.bgk[g][f];
      bvv_[nt] = p.bv[g][f]; gvv_[nt] = p.gv[g][f]; bbv_[nt] = p.bgv[g][f];
    }
    // k-GEMM
    bf16x8 af[4];
    f32x4 kc[4];
#pragma unroll
    for (int nt = 0; nt < 4; ++nt) { kc[nt].x = 0; kc[nt].y = 0; kc[nt].z = 0; kc[nt].w = 0; }
#pragma unroll
    for (int ks = 0; ks < 4; ++ks) {
      af[ks] = lda(stg, 256, ks, lane);
#pragma unroll
      for (int nt = 0; nt < 4; ++nt)
        kc[nt] = MFMA(af[ks], ldb(wkv, nt * 16, 128, ks, lane), kc[nt]);
    }
#pragma unroll
    for (int reg = 0; reg < 4; ++reg) {
      float s = 0.f;
#pragma unroll
      for (int nt = 0; nt < 4; ++nt) { kc[nt][reg] += bk_[nt]; s += kc[nt][reg]; }
      s += __shfl_xor(s, 1); s += __shfl_xor(s, 2); s += __shfl_xor(s, 4); s += __shfl_xor(s, 8);
      float mu = s * (1.f / 64.f);
      float v2 = 0.f;
#pragma unroll
      for (int nt = 0; nt < 4; ++nt) { float d = kc[nt][reg] - mu; v2 = fmaf(d, d, v2); }
      v2 += __shfl_xor(v2, 1); v2 += __shfl_xor(v2, 2); v2 += __shfl_xor(v2, 4); v2 += __shfl_xor(v2, 8);
      float rs = rsqrtf(v2 * (1.f / 64.f) + 1e-6f);
#pragma unroll
      for (int nt = 0; nt < 4; ++nt)
        kc[nt][reg] = (kc[nt][reg] - mu) * rs * gk_[nt] + bbk_[nt];
    }
    // scores: q from LDS (fp32, no shfl-broadcast)
    float qb[4];
#pragma unroll
    for (int nt = 0; nt < 4; ++nt) qb[nt] = qFp[(g * 4 + r) * 68 + nt * 16 + l15];
    float sreg[4];
#pragma unroll
    for (int reg = 0; reg < 4; ++reg) {
      float sp = qb[0]*kc[0][reg] + qb[1]*kc[1][reg] + qb[2]*kc[2][reg] + qb[3]*kc[3][reg];
      sp += __shfl_xor(sp, 1); sp += __shfl_xor(sp, 2); sp += __shfl_xor(sp, 4); sp += __shfl_xor(sp, 8);
      sreg[reg] = sp * 0.125f;
    }
    float mloc = -1e30f;
#pragma unroll
    for (int reg = 0; reg < 4; ++reg) {
      if (g == 0 && lg == 3 && reg == 3) sreg[reg] = -1e30f;
      mloc = fmaxf(mloc, sreg[reg]);
    }
    mloc = fmaxf(mloc, __shfl_xor(mloc, 16));
    mloc = fmaxf(mloc, __shfl_xor(mloc, 32));
    float pr[4], esum = 0.f;
#pragma unroll
    for (int reg = 0; reg < 4; ++reg) { pr[reg] = __expf(sreg[reg] - mloc); esum += pr[reg]; }
    esum += __shfl_xor(esum, 16);
    esum += __shfl_xor(esum, 32);
    const float inv = 1.f / esum;
    // v-GEMM (reuse af)
    f32x4 vc[4];
#pragma unroll
    for (int nt = 0; nt < 4; ++nt) { vc[nt].x = 0; vc[nt].y = 0; vc[nt].z = 0; vc[nt].w = 0; }
#pragma unroll
    for (int ks = 0; ks < 4; ++ks)
#pragma unroll
      for (int nt = 0; nt < 4; ++nt)
        vc[nt] = MFMA(af[ks], ldb(wkv, 64 + nt * 16, 128, ks, lane), vc[nt]);
#pragma unroll
    for (int reg = 0; reg < 4; ++reg) {
      float s = 0.f;
#pragma unroll
      for (int nt = 0; nt < 4; ++nt) { vc[nt][reg] += bvv_[nt]; s += vc[nt][reg]; }
      s += __shfl_xor(s, 1); s += __shfl_xor(s, 2); s += __shfl_xor(s, 4); s += __shfl_xor(s, 8);
      float mu = s * (1.f / 64.f);
      float v2 = 0.f;
#pragma unroll
      for (int nt = 0; nt < 4; ++nt) { float d = vc[nt][reg] - mu; v2 = fmaf(d, d, v2); }
      v2 += __shfl_xor(v2, 1); v2 += __shfl_xor(v2, 2); v2 += __shfl_xor(v2, 4); v2 += __shfl_xor(v2, 8);
      float rs = rsqrtf(v2 * (1.f / 64.f) + 1e-6f);
#pragma unroll
      for (int nt = 0; nt < 4; ++nt)
        vc[nt][reg] = (vc[nt][reg] - mu) * rs * gvv_[nt] + bbv_[nt];
    }
    // o = softmax @ v -> oF fp32
#pragma unroll
    for (int nt = 0; nt < 4; ++nt) {
      float op = pr[0]*vc[nt][0] + pr[1]*vc[nt][1] + pr[2]*vc[nt][2] + pr[3]*vc[nt][3];
      op += __shfl_xor(op, 16);
      op += __shfl_xor(op, 32);
      op *= inv;
      if (lg == 0) oFp[(g * 4 + r) * 68 + nt * 16 + l15] = op;
    }
    __syncthreads();
  }

  // ---- phase 3: oF -> oA (bf16, block-diag layout) ----
#pragma unroll
  for (int j = 0; j < 8; ++j) {
    int g = j >> 2;
    float v = oFp[j * 68 + lane];   // lane = feature 0-63
    int byte = j * 256 + (g * 64 + lane) * 2;
    byte ^= (j & 7) << 4;
    *(short*)(oA + byte) = (short)f2bf(v);
  }
  __syncthreads();

  // ---- phase 4: fc1 -> relu -> oA ----
  {
    f32x4 hc[4];
#pragma unroll
    for (int nt = 0; nt < 4; ++nt) { hc[nt].x = 0; hc[nt].y = 0; hc[nt].z = 0; hc[nt].w = 0; }
#pragma unroll
    for (int ks = 0; ks < 4; ++ks) {
      bf16x8 afo = lda(oA, 256, ks, lane);
#pragma unroll
      for (int nt = 0; nt < 4; ++nt)
        hc[nt] = MFMA(afo, ldb(ws + W1C, nt * 16, 128, ks, lane), hc[nt]);
    }
    __syncthreads();          // all reads of oA done before writes
    if (lane < 32) {
      const int g = lg;
#pragma unroll
      for (int nt = 0; nt < 4; ++nt) {
        float b1v = p.b1[g][nt * 16 + l15];
#pragma unroll
        for (int reg = 0; reg < 4; ++reg) {
          int m = 4 * lg + reg;
          float h = fmaxf(hc[nt][reg] + b1v, 0.f);
          int byte = m * 256 + (g * 64 + nt * 16 + l15) * 2;
          byte ^= (m & 7) << 4;
          *(short*)(oA + byte) = (short)f2bf(h);
        }
      }
    }
  }
  __syncthreads();

  // ---- phase 5: fc2 + write attention outputs ----
  {
    f32x4 oc[4];
#pragma unroll
    for (int nt = 0; nt < 4; ++nt) { oc[nt].x = 0; oc[nt].y = 0; oc[nt].z = 0; oc[nt].w = 0; }
#pragma unroll
    for (int ks = 0; ks < 4; ++ks) {
      bf16x8 afh = lda(oA, 256, ks, lane);
#pragma unroll
      for (int nt = 0; nt < 4; ++nt)
        oc[nt] = MFMA(afh, ldb(ws + W2C, nt * 16, 128, ks, lane), oc[nt]);
    }
    if (lane < 32) {
      const int g = lg;
#pragma unroll
      for (int nt = 0; nt < 4; ++nt) {
        float b2v = p.b2[g][nt * 16 + l15];
#pragma unroll
        for (int reg = 0; reg < 4; ++reg)
          p.out[(size_t)(rbase + reg) * OUTLEN + g * 64 + nt * 16 + l15] = oc[nt][reg] + b2v;
      }
    }
  }
  __syncthreads();

  // ---- phase 6: other-FC ----
#pragma unroll
  for (int j = 0; j < 10; ++j)
    *(unsigned long long*)(stg + j * 512 + lane * 8) = 0ull;
  __syncthreads();
#pragma unroll
  for (int j = 0; j < 3; ++j) {
    int i = j * 256 + lane * 4;
    if (i < 640) {
      int rr = i / 160, c = i % 160;
      float4 w = *(const float4*)(xb + rr * ROWLEN + 3968 + c);
      int b = rr * 320 + c * 2; b ^= (rr & 7) << 4;
      *(short4v*)(stg + b) = cvt4(w);
    }
  }
  __syncthreads();
  {
    f32x4 fc[4];
#pragma unroll
    for (int nt = 0; nt < 4; ++nt) { fc[nt].x = 0; fc[nt].y = 0; fc[nt].z = 0; fc[nt].w = 0; }
#pragma unroll
    for (int ks = 0; ks < 5; ++ks) {
      bf16x8 afx = lda(stg, 320, ks, lane);
#pragma unroll
      for (int nt = 0; nt < 4; ++nt)
        fc[nt] = MFMA(afx, ldb(ws + FCWC, nt * 16, 160, ks, lane), fc[nt]);
    }
    if (lg == 0) {
#pragma unroll
      for (int nt = 0; nt < 4; ++nt) {
        float fbv = p.fcb[nt * 16 + l15];
#pragma unroll
        for (int reg = 0; reg < 4; ++reg)
          p.out[(size_t)(rbase + reg) * OUTLEN + 128 + nt * 16 + l15] = fc[nt][reg] + fbv;
      }
    }
  }
}

extern "C" void kernel_launch(void* const* d_in, const int* in_sizes, int n_in,
                              void* d_out, int out_size, void* d_ws, size_t ws_size,
                              hipStream_t stream) {
  (void)n_in; (void)out_size; (void)ws_size;
  const float* const* in = (const float* const*)d_in;
  us* ws = (us*)d_ws;

  hipLaunchKernelGGL(prep, dim3(64), dim3(256), 0, stream,
                     in[1], in[3], in[5], in[13], in[15],
                     in[17], in[19], in[21], in[29], in[31],
                     in[33], ws);

  P p;
  p.inputs = in[0];
  p.bq[0] = in[2];  p.bq[1] = in[18];
  p.gq[0] = in[7];  p.gq[1] = in[23];
  p.bgq[0] = in[8]; p.bgq[1] = in[24];
  p.bk[0] = in[4];  p.bk[1] = in[20];
  p.gk[0] = in[9];  p.gk[1] = in[25];
  p.bgk[0] = in[10]; p.bgk[1] = in[26];
  p.bv[0] = in[6];  p.bv[1] = in[22];
  p.gv[0] = in[11]; p.gv[1] = in[27];
  p.bgv[0] = in[12]; p.bgv[1] = in[28];
  p.b1[0] = in[14]; p.b1[1] = in[30];
  p.b2[0] = in[16]; p.b2[1] = in[32];
  p.fcb = in[34];
  p.out = (float*)d_out;

  const int rows = in_sizes[0] / ROWLEN;
  hipLaunchKernelGGL(fused, dim3(rows >> 4), dim3(256), 0, stream, p, ws);
}